// Round 4
// baseline (6032.761 us; speedup 1.0000x reference)
//
#include <hip/hip_runtime.h>
#include <hip/hip_bf16.h>

#define EPSF 1e-8f

// One block = one batch element. 256 threads. All I/O float32 (per reference).
// Phase A (enc, per frame f=0..19): conv(4x4,s2,p1)x3 -> fc1 -> fc2 -> z_all[f]
// Phase B: context norm over the 20 timesteps (in LDS)
// Phase C: 20-step LSTM + k-NN memory scan -> logits + argmax
//
// LDS pool layout (floats):
//   z_all : smem[0 .. 2560)                       persistent
//   pool  : smem[2560 .. 15104)                   aliased:
//     enc : xs 1024 | c1s 8192 | c2s 2048 | c3s 512 | h1s 256 | w1s 512  (=12544)
//     scan: Msh 20*257=5140 | inp 384 | hsh 256 | kqr 256 | kqw 256 | vsh 256 (=6548)
__global__ __launch_bounds__(256) void fused_kernel(
    const float* __restrict__ x,
    const float* __restrict__ w1, const float* __restrict__ b1,
    const float* __restrict__ w2, const float* __restrict__ b2,
    const float* __restrict__ w3, const float* __restrict__ b3,
    const float* __restrict__ f1w, const float* __restrict__ f1b,
    const float* __restrict__ f2w, const float* __restrict__ f2b,
    const float* __restrict__ gamma, const float* __restrict__ beta,
    const float* __restrict__ wi,   // [1024,384]
    const float* __restrict__ wh,   // [1024,256]
    const float* __restrict__ lb,   // [1024]
    const float* __restrict__ wk,   // [256,256]
    const float* __restrict__ wwk,  // [256,256]
    const float* __restrict__ wv,   // [256,256]
    const float* __restrict__ wo,   // [4,512]
    const float* __restrict__ wob,  // [4]
    const float* __restrict__ mem_init,  // [20,256]
    float* __restrict__ out) {
  __shared__ float smem[15104];
  __shared__ float simr[20], simw[20], invq[2], wsel[2][4], ysh[4];
  __shared__ int isel[2][4];

  float* z_all = smem;               // 20*128
  float* pool  = smem + 2560;
  // enc aliases
  float* xs  = pool;                 // 1024
  float* c1s = pool + 1024;          // 8192
  float* c2s = pool + 9216;          // 2048
  float* c3s = pool + 11264;         // 512
  float* h1s = pool + 11776;         // 256
  float* w1s = pool + 12032;         // 512
  // scan aliases
  float* Msh   = pool;               // 5140 (20 rows x 257, padded)
  float* inp   = pool + 5140;        // 384: [z_t(128) | r(256)]
  float* hsh   = pool + 5524;        // 256
  float* kqr   = pool + 5780;        // 256
  float* kqw   = pool + 6036;        // 256
  float* vsh   = pool + 6292;        // 256

  const int tid = threadIdx.x;
  const int b = blockIdx.x;

  // conv1 weights once (stable across the frame loop)
  for (int i = tid; i < 512; i += 256) w1s[i] = w1[i];

  // ---------------- Phase A: encoder, 20 frames ----------------
  for (int f = 0; f < 20; ++f) {
    for (int i = tid; i < 1024; i += 256) xs[i] = x[(b * 20 + f) * 1024 + i];
    __syncthreads();

    // conv1: 1->32ch, 32x32 -> 16x16
    for (int i = 0; i < 32; ++i) {
      int idx = i * 256 + tid;
      int oc = idx >> 8, pix = idx & 255, oy = pix >> 4, ox = pix & 15;
      float acc = b1[oc];
      #pragma unroll
      for (int ky = 0; ky < 4; ++ky) {
        int iy = oy * 2 - 1 + ky;
        if ((unsigned)iy > 31u) continue;
        #pragma unroll
        for (int kx = 0; kx < 4; ++kx) {
          int ix = ox * 2 - 1 + kx;
          if ((unsigned)ix > 31u) continue;
          acc = fmaf(xs[iy * 32 + ix], w1s[oc * 16 + ky * 4 + kx], acc);
        }
      }
      c1s[idx] = fmaxf(acc, 0.f);
    }
    __syncthreads();

    // conv2: 32->32ch, 16x16 -> 8x8. thread: oc = tid>>3, pixels (tid&7)+8*i
    {
      int oc = tid >> 3, pg = tid & 7;
      float acc[8];
      float bb = b2[oc];
      #pragma unroll
      for (int i = 0; i < 8; ++i) acc[i] = bb;
      for (int ic = 0; ic < 32; ++ic) {
        const float* in = &c1s[ic * 256];
        const float* wv_ = &w2[(oc * 32 + ic) * 16];
        #pragma unroll
        for (int i = 0; i < 8; ++i) {
          int p = pg + 8 * i;
          int oy = p >> 3, ox = p & 7;
          #pragma unroll
          for (int ky = 0; ky < 4; ++ky) {
            int iy = oy * 2 - 1 + ky;
            if ((unsigned)iy > 15u) continue;
            #pragma unroll
            for (int kx = 0; kx < 4; ++kx) {
              int ix = ox * 2 - 1 + kx;
              if ((unsigned)ix > 15u) continue;
              acc[i] = fmaf(in[iy * 16 + ix], wv_[ky * 4 + kx], acc[i]);
            }
          }
        }
      }
      #pragma unroll
      for (int i = 0; i < 8; ++i) c2s[oc * 64 + pg + 8 * i] = fmaxf(acc[i], 0.f);
    }
    __syncthreads();

    // conv3: 32->32ch, 8x8 -> 4x4. thread: oc = tid>>3, pixels pg, pg+8
    {
      int oc = tid >> 3, pg = tid & 7;
      float bb = b3[oc];
      float acc0 = bb, acc1 = bb;
      int p0 = pg, p1 = pg + 8;
      int oy0 = p0 >> 2, ox0 = p0 & 3, oy1 = p1 >> 2, ox1 = p1 & 3;
      for (int ic = 0; ic < 32; ++ic) {
        const float* in = &c2s[ic * 64];
        const float* wv_ = &w3[(oc * 32 + ic) * 16];
        #pragma unroll
        for (int ky = 0; ky < 4; ++ky) {
          int iy0 = oy0 * 2 - 1 + ky, iy1 = oy1 * 2 - 1 + ky;
          #pragma unroll
          for (int kx = 0; kx < 4; ++kx) {
            float w = wv_[ky * 4 + kx];
            int ix0 = ox0 * 2 - 1 + kx, ix1 = ox1 * 2 - 1 + kx;
            if ((unsigned)iy0 <= 7u && (unsigned)ix0 <= 7u)
              acc0 = fmaf(in[iy0 * 8 + ix0], w, acc0);
            if ((unsigned)iy1 <= 7u && (unsigned)ix1 <= 7u)
              acc1 = fmaf(in[iy1 * 8 + ix1], w, acc1);
          }
        }
      }
      c3s[oc * 16 + p0] = fmaxf(acc0, 0.f);
      c3s[oc * 16 + p1] = fmaxf(acc1, 0.f);
    }
    __syncthreads();

    // fc1: 512 -> 256, relu
    {
      float acc = f1b[tid];
      const float* wr = f1w + tid * 512;
      for (int k = 0; k < 512; ++k) acc = fmaf(wr[k], c3s[k], acc);
      h1s[tid] = fmaxf(acc, 0.f);
    }
    __syncthreads();

    // fc2: 256 -> 128, relu -> z_all
    if (tid < 128) {
      float acc = f2b[tid];
      const float* wr = f2w + tid * 256;
      for (int k = 0; k < 256; ++k) acc = fmaf(wr[k], h1s[k], acc);
      z_all[f * 128 + tid] = fmaxf(acc, 0.f);
    }
    __syncthreads();  // protect h1s/c3s before next frame reuses pool
  }

  // ---------------- Phase B: context norm over time ----------------
  if (tid < 128) {
    float mu = 0.f;
    #pragma unroll
    for (int t = 0; t < 20; ++t) mu += z_all[t * 128 + tid];
    mu *= (1.f / 20.f);
    float var = 0.f;
    #pragma unroll
    for (int t = 0; t < 20; ++t) {
      float dd = z_all[t * 128 + tid] - mu;
      var = fmaf(dd, dd, var);
    }
    var *= (1.f / 19.f);
    float inv = 1.f / sqrtf(var + EPSF);
    float ga = gamma[tid], be = beta[tid];
    #pragma unroll
    for (int t = 0; t < 20; ++t)
      z_all[t * 128 + tid] = fmaf((z_all[t * 128 + tid] - mu) * inv, ga, be);
  }

  // scan-state init (pool region is free now; z_all untouched)
  for (int idx = tid; idx < 20 * 256; idx += 256)
    Msh[(idx >> 8) * 257 + (idx & 255)] = mem_init[idx];
  hsh[tid] = 0.f;
  inp[128 + tid] = 0.f;
  float c_reg = 0.f;
  __syncthreads();

  // ---------------- Phase C: 20-step scan ----------------
  const int u = tid;
  for (int t = 0; t < 20; ++t) {
    if (u < 128) inp[u] = z_all[t * 128 + u];
    __syncthreads();

    // gates = [z,r] @ wi.T + h @ wh.T + b ; rows (i,f,g,o) for unit u
    float a[4];
    #pragma unroll
    for (int g = 0; g < 4; ++g) {
      int row = g * 256 + u;
      float acc = lb[row];
      const float* wr = wi + row * 384;
      for (int k = 0; k < 384; ++k) acc = fmaf(wr[k], inp[k], acc);
      const float* hr = wh + row * 256;
      for (int k = 0; k < 256; ++k) acc = fmaf(hr[k], hsh[k], acc);
      a[g] = acc;
    }
    __syncthreads();  // all reads of hsh done before overwrite

    {
      float ig = 1.f / (1.f + expf(-a[0]));
      float fg = 1.f / (1.f + expf(-a[1]));
      float gg = tanhf(a[2]);
      float og = 1.f / (1.f + expf(-a[3]));
      c_reg = fg * c_reg + ig * gg;
      hsh[u] = og * tanhf(c_reg);
    }
    __syncthreads();

    // head projections
    {
      float sk = 0.f, sw = 0.f, sv = 0.f;
      const float* rk = wk + u * 256;
      const float* rw = wwk + u * 256;
      const float* rv = wv + u * 256;
      for (int k = 0; k < 256; ++k) {
        float hv = hsh[k];
        sk = fmaf(rk[k], hv, sk);
        sw = fmaf(rw[k], hv, sw);
        sv = fmaf(rv[k], hv, sv);
      }
      kqr[u] = sk;
      kqw[u] = sw;
      vsh[u] = tanhf(sv);
    }
    __syncthreads();

    // per-slot norms + sims; query norms on threads 20/21
    if (u < 20) {
      const float* Mr = &Msh[u * 257];
      float ss = 0.f, s1 = 0.f, s2 = 0.f;
      for (int k = 0; k < 256; ++k) {
        float m = Mr[k];
        ss = fmaf(m, m, ss);
        s1 = fmaf(kqr[k], m, s1);
        s2 = fmaf(kqw[k], m, s2);
      }
      float inv = 1.f / (sqrtf(ss) + EPSF);
      simr[u] = s1 * inv;
      simw[u] = s2 * inv;
    } else if (u == 20 || u == 21) {
      const float* q = (u == 20) ? kqr : kqw;
      float qq = 0.f;
      for (int k = 0; k < 256; ++k) qq = fmaf(q[k], q[k], qq);
      invq[u - 20] = 1.f / (sqrtf(qq) + EPSF);
    }
    __syncthreads();

    // top-4 (stable: strict >, lowest index on tie) + softmax
    if (u < 2) {
      const float* sims = (u == 0) ? simr : simw;
      float inv = invq[u];
      unsigned mask = 0;
      float tv[4];
      int ti[4];
      for (int j = 0; j < 4; ++j) {
        float best = -3.4e38f;
        int bx = 0;
        for (int n = 0; n < 20; ++n)
          if (!((mask >> n) & 1u) && sims[n] > best) { best = sims[n]; bx = n; }
        mask |= 1u << bx;
        tv[j] = best * inv;
        ti[j] = bx;
      }
      float e0 = 1.f;
      float e1 = expf(tv[1] - tv[0]);
      float e2 = expf(tv[2] - tv[0]);
      float e3 = expf(tv[3] - tv[0]);
      float s = e0 + e1 + e2 + e3;
      wsel[u][0] = e0 / s; wsel[u][1] = e1 / s; wsel[u][2] = e2 / s; wsel[u][3] = e3 / s;
      isel[u][0] = ti[0]; isel[u][1] = ti[1]; isel[u][2] = ti[2]; isel[u][3] = ti[3];
    }
    __syncthreads();

    // read gather (old M) then weighted scatter-add; column u thread-exclusive
    {
      float rvv = 0.f;
      #pragma unroll
      for (int j = 0; j < 4; ++j)
        rvv = fmaf(wsel[0][j], Msh[isel[0][j] * 257 + u], rvv);
      float vv = vsh[u];
      #pragma unroll
      for (int j = 0; j < 4; ++j)
        Msh[isel[1][j] * 257 + u] += wsel[1][j] * vv;
      inp[128 + u] = rvv;  // r for next step / output
    }
    __syncthreads();
  }

  // epilogue: y = [h, r] @ wo.T + wo_b at t=T-1; argmax (first max wins)
  if (u < 4) {
    float acc = wob[u];
    const float* wr = wo + u * 512;
    for (int k = 0; k < 256; ++k) acc = fmaf(wr[k], hsh[k], acc);
    for (int k = 0; k < 256; ++k) acc = fmaf(wr[256 + k], inp[128 + k], acc);
    ysh[u] = acc;
    out[b * 4 + u] = acc;
  }
  __syncthreads();
  if (u == 0) {
    float best = ysh[0];
    int bx = 0;
    #pragma unroll
    for (int o = 1; o < 4; ++o)
      if (ysh[o] > best) { best = ysh[o]; bx = o; }
    out[1024 + b] = (float)bx;
  }
}

// ---------- launch: ONE kernel, no workspace, all float32 ----------
extern "C" void kernel_launch(void* const* d_in, const int* in_sizes, int n_in,
                              void* d_out, int out_size, void* d_ws, size_t ws_size,
                              hipStream_t stream) {
  fused_kernel<<<256, 256, 0, stream>>>(
      (const float*)d_in[0],
      (const float*)d_in[1],  (const float*)d_in[2],
      (const float*)d_in[3],  (const float*)d_in[4],
      (const float*)d_in[5],  (const float*)d_in[6],
      (const float*)d_in[7],  (const float*)d_in[8],
      (const float*)d_in[9],  (const float*)d_in[10],
      (const float*)d_in[11], (const float*)d_in[12],
      (const float*)d_in[13], (const float*)d_in[14],
      (const float*)d_in[15], (const float*)d_in[16],
      (const float*)d_in[17], (const float*)d_in[18],
      (const float*)d_in[19], (const float*)d_in[20],
      (const float*)d_in[21],
      (float*)d_out);
}

// Round 5
// 1759.060 us; speedup vs baseline: 3.4295x; 3.4295x over previous
//
#include <hip/hip_runtime.h>
#include <hip/hip_bf16.h>

#define EPSF 1e-8f

// ---- workspace layout (floats) ----
#define OFF_WIT 0               // wiT [384][1024]
#define N_WIT   393216
#define OFF_WHT 393216          // whT [256][1024]
#define N_WHT   262144
#define OFF_PKT 655360          // pkT [256][256][4] = {wk,wwk,wv,0}[o][k]
#define N_PKT   262144
#define OFF_F1T 917504          // f1wT [512][256]
#define N_F1T   131072
#define OFF_F2T 1048576         // f2wT [256][128]
#define N_F2T   32768
#define OFF_Z   1081344         // z [5120][128]
#define N_Z     655360
#define WS_FLOATS 1736704       // 6,946,816 bytes

// ---------- pack: transpose weights into ws (once per launch) ----------
__global__ __launch_bounds__(256) void pack_kernel(
    const float* __restrict__ wi, const float* __restrict__ wh,
    const float* __restrict__ wk, const float* __restrict__ wwk,
    const float* __restrict__ wv,
    const float* __restrict__ f1w, const float* __restrict__ f2w,
    float* __restrict__ ws) {
  int id = blockIdx.x * 256 + threadIdx.x;
  if (id < N_WIT) {  // out[k*1024 + r] = wi[r*384 + k]
    int k = id >> 10, r = id & 1023;
    ws[OFF_WIT + id] = wi[r * 384 + k];
    return;
  }
  id -= N_WIT;
  if (id < N_WHT) {
    int k = id >> 10, r = id & 1023;
    ws[OFF_WHT + id] = wh[r * 256 + k];
    return;
  }
  id -= N_WHT;
  if (id < N_PKT) {  // out[((k*256)+o)*4 + m]
    int m = id & 3, o = (id >> 2) & 255, k = id >> 10;
    float v = 0.f;
    if (m == 0) v = wk[o * 256 + k];
    else if (m == 1) v = wwk[o * 256 + k];
    else if (m == 2) v = wv[o * 256 + k];
    ws[OFF_PKT + id] = v;
    return;
  }
  id -= N_PKT;
  if (id < N_F1T) {  // out[k*256 + o] = f1w[o*512 + k]
    int k = id >> 8, o = id & 255;
    ws[OFF_F1T + id] = f1w[o * 512 + k];
    return;
  }
  id -= N_F1T;
  if (id < N_F2T) {  // out[k*128 + o] = f2w[o*256 + k]
    int k = id >> 7, o = id & 127;
    ws[OFF_F2T + id] = f2w[o * 256 + k];
  }
}

// ---------- encoder: one block per frame (grid 5120) ----------
__global__ __launch_bounds__(256) void enc_kernel(
    const float* __restrict__ x,
    const float* __restrict__ w1, const float* __restrict__ b1,
    const float* __restrict__ w2, const float* __restrict__ b2,
    const float* __restrict__ w3, const float* __restrict__ b3,
    const float* __restrict__ f1b, const float* __restrict__ f2b,
    float* __restrict__ ws) {
  __shared__ __align__(16) float xs[1024];
  __shared__ __align__(16) float c1s[32 * 256];
  __shared__ __align__(16) float c2s[32 * 64];
  __shared__ __align__(16) float c3s[512];
  __shared__ __align__(16) float h1s[256];
  __shared__ __align__(16) float w1s[512];

  const float* __restrict__ f1wT = ws + OFF_F1T;
  const float* __restrict__ f2wT = ws + OFF_F2T;
  float* __restrict__ z = ws + OFF_Z;

  const int f = blockIdx.x;  // = b*20 + t
  const int tid = threadIdx.x;

  for (int i = tid; i < 1024; i += 256) xs[i] = x[f * 1024 + i];
  for (int i = tid; i < 512; i += 256) w1s[i] = w1[i];
  __syncthreads();

  // conv1: 1->32ch, 32x32 -> 16x16
  for (int i = 0; i < 32; ++i) {
    int idx = i * 256 + tid;
    int oc = idx >> 8, pix = idx & 255, oy = pix >> 4, ox = pix & 15;
    float acc = b1[oc];
    #pragma unroll
    for (int ky = 0; ky < 4; ++ky) {
      int iy = oy * 2 - 1 + ky;
      if ((unsigned)iy > 31u) continue;
      #pragma unroll
      for (int kx = 0; kx < 4; ++kx) {
        int ix = ox * 2 - 1 + kx;
        if ((unsigned)ix > 31u) continue;
        acc = fmaf(xs[iy * 32 + ix], w1s[oc * 16 + ky * 4 + kx], acc);
      }
    }
    c1s[idx] = fmaxf(acc, 0.f);
  }
  __syncthreads();

  // conv2: 32->32ch, 16x16 -> 8x8
  {
    int oc = tid >> 3, pg = tid & 7;
    float acc[8];
    float bb = b2[oc];
    #pragma unroll
    for (int i = 0; i < 8; ++i) acc[i] = bb;
    for (int ic = 0; ic < 32; ++ic) {
      const float* in = &c1s[ic * 256];
      const float4* wp = (const float4*)(w2 + (oc * 32 + ic) * 16);
      float4 q0 = wp[0], q1 = wp[1], q2 = wp[2], q3 = wp[3];
      float wv_[16] = {q0.x, q0.y, q0.z, q0.w, q1.x, q1.y, q1.z, q1.w,
                       q2.x, q2.y, q2.z, q2.w, q3.x, q3.y, q3.z, q3.w};
      #pragma unroll
      for (int i = 0; i < 8; ++i) {
        int p = pg + 8 * i;
        int oy = p >> 3, ox = p & 7;
        #pragma unroll
        for (int ky = 0; ky < 4; ++ky) {
          int iy = oy * 2 - 1 + ky;
          if ((unsigned)iy > 15u) continue;
          #pragma unroll
          for (int kx = 0; kx < 4; ++kx) {
            int ix = ox * 2 - 1 + kx;
            if ((unsigned)ix > 15u) continue;
            acc[i] = fmaf(in[iy * 16 + ix], wv_[ky * 4 + kx], acc[i]);
          }
        }
      }
    }
    #pragma unroll
    for (int i = 0; i < 8; ++i) c2s[oc * 64 + pg + 8 * i] = fmaxf(acc[i], 0.f);
  }
  __syncthreads();

  // conv3: 32->32ch, 8x8 -> 4x4
  {
    int oc = tid >> 3, pg = tid & 7;
    float bb = b3[oc];
    float acc0 = bb, acc1 = bb;
    int p0 = pg, p1 = pg + 8;
    int oy0 = p0 >> 2, ox0 = p0 & 3, oy1 = p1 >> 2, ox1 = p1 & 3;
    for (int ic = 0; ic < 32; ++ic) {
      const float* in = &c2s[ic * 64];
      const float4* wp = (const float4*)(w3 + (oc * 32 + ic) * 16);
      float4 q0 = wp[0], q1 = wp[1], q2 = wp[2], q3 = wp[3];
      float wv_[16] = {q0.x, q0.y, q0.z, q0.w, q1.x, q1.y, q1.z, q1.w,
                       q2.x, q2.y, q2.z, q2.w, q3.x, q3.y, q3.z, q3.w};
      #pragma unroll
      for (int ky = 0; ky < 4; ++ky) {
        int iy0 = oy0 * 2 - 1 + ky, iy1 = oy1 * 2 - 1 + ky;
        #pragma unroll
        for (int kx = 0; kx < 4; ++kx) {
          float w = wv_[ky * 4 + kx];
          int ix0 = ox0 * 2 - 1 + kx, ix1 = ox1 * 2 - 1 + kx;
          if ((unsigned)iy0 <= 7u && (unsigned)ix0 <= 7u)
            acc0 = fmaf(in[iy0 * 8 + ix0], w, acc0);
          if ((unsigned)iy1 <= 7u && (unsigned)ix1 <= 7u)
            acc1 = fmaf(in[iy1 * 8 + ix1], w, acc1);
        }
      }
    }
    c3s[oc * 16 + p0] = fmaxf(acc0, 0.f);
    c3s[oc * 16 + p1] = fmaxf(acc1, 0.f);
  }
  __syncthreads();

  // fc1: 512 -> 256, relu (coalesced via f1wT)
  {
    float acc = f1b[tid];
    for (int k4 = 0; k4 < 128; ++k4) {
      float4 cv = ((const float4*)c3s)[k4];
      int kb = k4 * 4;
      acc = fmaf(f1wT[(kb + 0) * 256 + tid], cv.x, acc);
      acc = fmaf(f1wT[(kb + 1) * 256 + tid], cv.y, acc);
      acc = fmaf(f1wT[(kb + 2) * 256 + tid], cv.z, acc);
      acc = fmaf(f1wT[(kb + 3) * 256 + tid], cv.w, acc);
    }
    h1s[tid] = fmaxf(acc, 0.f);
  }
  __syncthreads();

  // fc2: 256 -> 128, relu -> z
  if (tid < 128) {
    float acc = f2b[tid];
    for (int k4 = 0; k4 < 64; ++k4) {
      float4 hv = ((const float4*)h1s)[k4];
      int kb = k4 * 4;
      acc = fmaf(f2wT[(kb + 0) * 128 + tid], hv.x, acc);
      acc = fmaf(f2wT[(kb + 1) * 128 + tid], hv.y, acc);
      acc = fmaf(f2wT[(kb + 2) * 128 + tid], hv.z, acc);
      acc = fmaf(f2wT[(kb + 3) * 128 + tid], hv.w, acc);
    }
    z[f * 128 + tid] = fmaxf(acc, 0.f);
  }
}

// ---------- context norm over time ----------
__global__ __launch_bounds__(256) void norm_kernel(
    float* __restrict__ ws,
    const float* __restrict__ gamma, const float* __restrict__ beta) {
  float* z = ws + OFF_Z;
  int g = blockIdx.x * 256 + threadIdx.x;  // B*D = 32768
  int b = g >> 7, d = g & 127;
  float vals[20];
  float mu = 0.f;
  #pragma unroll
  for (int t = 0; t < 20; ++t) {
    float v = z[(b * 20 + t) * 128 + d];
    vals[t] = v;
    mu += v;
  }
  mu *= (1.f / 20.f);
  float var = 0.f;
  #pragma unroll
  for (int t = 0; t < 20; ++t) {
    float dd = vals[t] - mu;
    var = fmaf(dd, dd, var);
  }
  var *= (1.f / 19.f);
  float inv = 1.f / sqrtf(var + EPSF);
  float ga = gamma[d], be = beta[d];
  #pragma unroll
  for (int t = 0; t < 20; ++t)
    z[(b * 20 + t) * 128 + d] = fmaf((vals[t] - mu) * inv, ga, be);
}

// ---------- scan: 2 batch elements per block, 128 blocks ----------
__global__ __launch_bounds__(256) void scan_kernel(
    const float* __restrict__ ws,
    const float* __restrict__ lb, const float* __restrict__ wo,
    const float* __restrict__ wob, const float* __restrict__ mem_init,
    float* __restrict__ out) {
  __shared__ float Msh[2][20 * 257];
  __shared__ __align__(16) float gsh[2][1024];
  __shared__ __align__(16) float inp[2][384];   // [z(128) | r(256)]
  __shared__ __align__(16) float hsh[2][256];
  __shared__ float kq[2][2][256];               // [bl][head][k]
  __shared__ float vsh[2][256];
  __shared__ float sims[2][2][20];
  __shared__ float invq[2][2];
  __shared__ float wsel[2][2][4];
  __shared__ int isel[2][2][4];
  __shared__ float ysh[2][4];

  const int u = threadIdx.x;
  const int b0 = blockIdx.x * 2;
  const float4* wiT4 = (const float4*)(ws + OFF_WIT);  // [384][256 x float4]
  const float4* whT4 = (const float4*)(ws + OFF_WHT);  // [256][256 x float4]
  const float4* pkT4 = (const float4*)(ws + OFF_PKT);  // [256][256] -> {wk,wwk,wv,0}
  const float* zz = ws + OFF_Z;

  #pragma unroll
  for (int bl = 0; bl < 2; ++bl)
    for (int idx = u; idx < 5120; idx += 256)
      Msh[bl][(idx >> 8) * 257 + (idx & 255)] = mem_init[idx];
  hsh[0][u] = 0.f; hsh[1][u] = 0.f;
  inp[0][128 + u] = 0.f; inp[1][128 + u] = 0.f;
  float c0 = 0.f, c1 = 0.f;
  const float4 bias = ((const float4*)lb)[u];  // rows 4u..4u+3
  __syncthreads();

  for (int t = 0; t < 20; ++t) {
    if (u < 128) {
      inp[0][u] = zz[(b0 * 20 + t) * 128 + u];
      inp[1][u] = zz[((b0 + 1) * 20 + t) * 128 + u];
    }
    __syncthreads();

    // gates: thread u computes rows 4u..4u+3 for both batch elements
    float A0[4] = {bias.x, bias.y, bias.z, bias.w};
    float A1[4] = {bias.x, bias.y, bias.z, bias.w};
    for (int k4 = 0; k4 < 96; ++k4) {
      float4 i0 = ((const float4*)inp[0])[k4];
      float4 i1 = ((const float4*)inp[1])[k4];
      float f0[4] = {i0.x, i0.y, i0.z, i0.w};
      float f1[4] = {i1.x, i1.y, i1.z, i1.w};
      #pragma unroll
      for (int j = 0; j < 4; ++j) {
        float4 w = wiT4[(k4 * 4 + j) * 256 + u];
        A0[0] = fmaf(w.x, f0[j], A0[0]); A0[1] = fmaf(w.y, f0[j], A0[1]);
        A0[2] = fmaf(w.z, f0[j], A0[2]); A0[3] = fmaf(w.w, f0[j], A0[3]);
        A1[0] = fmaf(w.x, f1[j], A1[0]); A1[1] = fmaf(w.y, f1[j], A1[1]);
        A1[2] = fmaf(w.z, f1[j], A1[2]); A1[3] = fmaf(w.w, f1[j], A1[3]);
      }
    }
    for (int k4 = 0; k4 < 64; ++k4) {
      float4 h0 = ((const float4*)hsh[0])[k4];
      float4 h1 = ((const float4*)hsh[1])[k4];
      float f0[4] = {h0.x, h0.y, h0.z, h0.w};
      float f1[4] = {h1.x, h1.y, h1.z, h1.w};
      #pragma unroll
      for (int j = 0; j < 4; ++j) {
        float4 w = whT4[(k4 * 4 + j) * 256 + u];
        A0[0] = fmaf(w.x, f0[j], A0[0]); A0[1] = fmaf(w.y, f0[j], A0[1]);
        A0[2] = fmaf(w.z, f0[j], A0[2]); A0[3] = fmaf(w.w, f0[j], A0[3]);
        A1[0] = fmaf(w.x, f1[j], A1[0]); A1[1] = fmaf(w.y, f1[j], A1[1]);
        A1[2] = fmaf(w.z, f1[j], A1[2]); A1[3] = fmaf(w.w, f1[j], A1[3]);
      }
    }
    ((float4*)gsh[0])[u] = make_float4(A0[0], A0[1], A0[2], A0[3]);
    ((float4*)gsh[1])[u] = make_float4(A1[0], A1[1], A1[2], A1[3]);
    __syncthreads();

    // LSTM cell (torch order i,f,g,o); unit u, both bl
    {
      float i0 = gsh[0][u], fg0 = gsh[0][256 + u], g0 = gsh[0][512 + u], o0 = gsh[0][768 + u];
      float i1 = gsh[1][u], fg1 = gsh[1][256 + u], g1 = gsh[1][512 + u], o1 = gsh[1][768 + u];
      c0 = (1.f / (1.f + expf(-fg0))) * c0 + (1.f / (1.f + expf(-i0))) * tanhf(g0);
      c1 = (1.f / (1.f + expf(-fg1))) * c1 + (1.f / (1.f + expf(-i1))) * tanhf(g1);
      hsh[0][u] = (1.f / (1.f + expf(-o0))) * tanhf(c0);
      hsh[1][u] = (1.f / (1.f + expf(-o1))) * tanhf(c1);
    }
    __syncthreads();

    // head projections: pkT float4 = {wk,wwk,wv,0}[u][k]
    {
      float sk0 = 0.f, sk1 = 0.f, sw0 = 0.f, sw1 = 0.f, sv0 = 0.f, sv1 = 0.f;
      for (int k4 = 0; k4 < 64; ++k4) {
        float4 h0 = ((const float4*)hsh[0])[k4];
        float4 h1 = ((const float4*)hsh[1])[k4];
        float f0[4] = {h0.x, h0.y, h0.z, h0.w};
        float f1[4] = {h1.x, h1.y, h1.z, h1.w};
        #pragma unroll
        for (int j = 0; j < 4; ++j) {
          float4 w = pkT4[(k4 * 4 + j) * 256 + u];
          sk0 = fmaf(w.x, f0[j], sk0); sk1 = fmaf(w.x, f1[j], sk1);
          sw0 = fmaf(w.y, f0[j], sw0); sw1 = fmaf(w.y, f1[j], sw1);
          sv0 = fmaf(w.z, f0[j], sv0); sv1 = fmaf(w.z, f1[j], sv1);
        }
      }
      kq[0][0][u] = sk0; kq[0][1][u] = sw0; vsh[0][u] = tanhf(sv0);
      kq[1][0][u] = sk1; kq[1][1][u] = sw1; vsh[1][u] = tanhf(sv1);
    }
    __syncthreads();

    // per-slot norms + sims (8 lanes/slot, shfl-reduce); query norms on u=160..163
    if (u < 160) {
      int n = u >> 3, l = u & 7;
      #pragma unroll
      for (int bl = 0; bl < 2; ++bl) {
        const float* Mr = &Msh[bl][n * 257];
        float ss = 0.f, s1 = 0.f, s2 = 0.f;
        for (int i = 0; i < 32; ++i) {
          int k = l + 8 * i;
          float m = Mr[k];
          ss = fmaf(m, m, ss);
          s1 = fmaf(kq[bl][0][k], m, s1);
          s2 = fmaf(kq[bl][1][k], m, s2);
        }
        ss += __shfl_xor(ss, 1); s1 += __shfl_xor(s1, 1); s2 += __shfl_xor(s2, 1);
        ss += __shfl_xor(ss, 2); s1 += __shfl_xor(s1, 2); s2 += __shfl_xor(s2, 2);
        ss += __shfl_xor(ss, 4); s1 += __shfl_xor(s1, 4); s2 += __shfl_xor(s2, 4);
        if (l == 0) {
          float inv = 1.f / (sqrtf(ss) + EPSF);
          sims[bl][0][n] = s1 * inv;
          sims[bl][1][n] = s2 * inv;
        }
      }
    } else if (u < 164) {
      int bl2 = (u - 160) >> 1, hd = u & 1;
      float qq = 0.f;
      for (int k = 0; k < 256; ++k) {
        float q = kq[bl2][hd][k];
        qq = fmaf(q, q, qq);
      }
      invq[bl2][hd] = 1.f / (sqrtf(qq) + EPSF);
    }
    __syncthreads();

    // top-4 (strict >, lowest index on tie) + softmax; 4 threads: (bl, head)
    if (u < 4) {
      int bl = u >> 1, hd = u & 1;
      const float* sm = sims[bl][hd];
      float inv = invq[bl][hd];
      unsigned mask = 0;
      float tv[4];
      int ti[4];
      for (int j = 0; j < 4; ++j) {
        float best = -3.4e38f;
        int bx = 0;
        for (int n = 0; n < 20; ++n)
          if (!((mask >> n) & 1u) && sm[n] > best) { best = sm[n]; bx = n; }
        mask |= 1u << bx;
        tv[j] = best * inv;
        ti[j] = bx;
      }
      float e0 = 1.f;
      float e1 = expf(tv[1] - tv[0]);
      float e2 = expf(tv[2] - tv[0]);
      float e3 = expf(tv[3] - tv[0]);
      float s = e0 + e1 + e2 + e3;
      wsel[bl][hd][0] = e0 / s; wsel[bl][hd][1] = e1 / s;
      wsel[bl][hd][2] = e2 / s; wsel[bl][hd][3] = e3 / s;
      isel[bl][hd][0] = ti[0]; isel[bl][hd][1] = ti[1];
      isel[bl][hd][2] = ti[2]; isel[bl][hd][3] = ti[3];
    }
    __syncthreads();

    // read gather (old M) then weighted scatter-add; column u thread-exclusive
    #pragma unroll
    for (int bl = 0; bl < 2; ++bl) {
      float rvv = 0.f;
      #pragma unroll
      for (int j = 0; j < 4; ++j)
        rvv = fmaf(wsel[bl][0][j], Msh[bl][isel[bl][0][j] * 257 + u], rvv);
      float vv = vsh[bl][u];
      #pragma unroll
      for (int j = 0; j < 4; ++j)
        Msh[bl][isel[bl][1][j] * 257 + u] += wsel[bl][1][j] * vv;
      inp[bl][128 + u] = rvv;
    }
    __syncthreads();
  }

  // epilogue: y = [h, r] @ wo.T + wo_b; argmax (first max wins)
  if (u < 8) {
    int bl = u >> 2, o = u & 3;
    float acc = wob[o];
    const float* wr = wo + o * 512;
    for (int k = 0; k < 256; ++k) acc = fmaf(wr[k], hsh[bl][k], acc);
    for (int k = 0; k < 256; ++k) acc = fmaf(wr[256 + k], inp[bl][128 + k], acc);
    ysh[bl][o] = acc;
    out[(b0 + bl) * 4 + o] = acc;
  }
  __syncthreads();
  if (u < 2) {
    float best = ysh[u][0];
    int bx = 0;
    #pragma unroll
    for (int o = 1; o < 4; ++o)
      if (ysh[u][o] > best) { best = ysh[u][o]; bx = o; }
    out[1024 + b0 + u] = (float)bx;
  }
}

// ---------- fallback: proven round-4 single fused kernel (no workspace) ----------
__global__ __launch_bounds__(256) void fused_kernel(
    const float* __restrict__ x,
    const float* __restrict__ w1, const float* __restrict__ b1,
    const float* __restrict__ w2, const float* __restrict__ b2,
    const float* __restrict__ w3, const float* __restrict__ b3,
    const float* __restrict__ f1w, const float* __restrict__ f1b,
    const float* __restrict__ f2w, const float* __restrict__ f2b,
    const float* __restrict__ gamma, const float* __restrict__ beta,
    const float* __restrict__ wi, const float* __restrict__ wh,
    const float* __restrict__ lb, const float* __restrict__ wk,
    const float* __restrict__ wwk, const float* __restrict__ wv,
    const float* __restrict__ wo, const float* __restrict__ wob,
    const float* __restrict__ mem_init, float* __restrict__ out) {
  __shared__ float smem[15104];
  __shared__ float simr[20], simw[20], invq[2], wsel[2][4], ysh[4];
  __shared__ int isel[2][4];
  float* z_all = smem;
  float* pool = smem + 2560;
  float* xs = pool;
  float* c1s = pool + 1024;
  float* c2s = pool + 9216;
  float* c3s = pool + 11264;
  float* h1s = pool + 11776;
  float* w1s = pool + 12032;
  float* Msh = pool;
  float* inp = pool + 5140;
  float* hsh = pool + 5524;
  float* kqr = pool + 5780;
  float* kqw = pool + 6036;
  float* vsh = pool + 6292;
  const int tid = threadIdx.x;
  const int b = blockIdx.x;
  for (int i = tid; i < 512; i += 256) w1s[i] = w1[i];
  for (int f = 0; f < 20; ++f) {
    for (int i = tid; i < 1024; i += 256) xs[i] = x[(b * 20 + f) * 1024 + i];
    __syncthreads();
    for (int i = 0; i < 32; ++i) {
      int idx = i * 256 + tid;
      int oc = idx >> 8, pix = idx & 255, oy = pix >> 4, ox = pix & 15;
      float acc = b1[oc];
      for (int ky = 0; ky < 4; ++ky) {
        int iy = oy * 2 - 1 + ky;
        if ((unsigned)iy > 31u) continue;
        for (int kx = 0; kx < 4; ++kx) {
          int ix = ox * 2 - 1 + kx;
          if ((unsigned)ix > 31u) continue;
          acc = fmaf(xs[iy * 32 + ix], w1s[oc * 16 + ky * 4 + kx], acc);
        }
      }
      c1s[idx] = fmaxf(acc, 0.f);
    }
    __syncthreads();
    {
      int oc = tid >> 3, pg = tid & 7;
      float acc[8];
      float bb = b2[oc];
      for (int i = 0; i < 8; ++i) acc[i] = bb;
      for (int ic = 0; ic < 32; ++ic) {
        const float* in = &c1s[ic * 256];
        const float* wv_ = &w2[(oc * 32 + ic) * 16];
        for (int i = 0; i < 8; ++i) {
          int p = pg + 8 * i;
          int oy = p >> 3, ox = p & 7;
          for (int ky = 0; ky < 4; ++ky) {
            int iy = oy * 2 - 1 + ky;
            if ((unsigned)iy > 15u) continue;
            for (int kx = 0; kx < 4; ++kx) {
              int ix = ox * 2 - 1 + kx;
              if ((unsigned)ix > 15u) continue;
              acc[i] = fmaf(in[iy * 16 + ix], wv_[ky * 4 + kx], acc[i]);
            }
          }
        }
      }
      for (int i = 0; i < 8; ++i) c2s[oc * 64 + pg + 8 * i] = fmaxf(acc[i], 0.f);
    }
    __syncthreads();
    {
      int oc = tid >> 3, pg = tid & 7;
      float bb = b3[oc];
      float acc0 = bb, acc1 = bb;
      int p0 = pg, p1 = pg + 8;
      int oy0 = p0 >> 2, ox0 = p0 & 3, oy1 = p1 >> 2, ox1 = p1 & 3;
      for (int ic = 0; ic < 32; ++ic) {
        const float* in = &c2s[ic * 64];
        const float* wv_ = &w3[(oc * 32 + ic) * 16];
        for (int ky = 0; ky < 4; ++ky) {
          int iy0 = oy0 * 2 - 1 + ky, iy1 = oy1 * 2 - 1 + ky;
          for (int kx = 0; kx < 4; ++kx) {
            float w = wv_[ky * 4 + kx];
            int ix0 = ox0 * 2 - 1 + kx, ix1 = ox1 * 2 - 1 + kx;
            if ((unsigned)iy0 <= 7u && (unsigned)ix0 <= 7u)
              acc0 = fmaf(in[iy0 * 8 + ix0], w, acc0);
            if ((unsigned)iy1 <= 7u && (unsigned)ix1 <= 7u)
              acc1 = fmaf(in[iy1 * 8 + ix1], w, acc1);
          }
        }
      }
      c3s[oc * 16 + p0] = fmaxf(acc0, 0.f);
      c3s[oc * 16 + p1] = fmaxf(acc1, 0.f);
    }
    __syncthreads();
    {
      float acc = f1b[tid];
      const float* wr = f1w + tid * 512;
      for (int k = 0; k < 512; ++k) acc = fmaf(wr[k], c3s[k], acc);
      h1s[tid] = fmaxf(acc, 0.f);
    }
    __syncthreads();
    if (tid < 128) {
      float acc = f2b[tid];
      const float* wr = f2w + tid * 256;
      for (int k = 0; k < 256; ++k) acc = fmaf(wr[k], h1s[k], acc);
      z_all[f * 128 + tid] = fmaxf(acc, 0.f);
    }
    __syncthreads();
  }
  if (tid < 128) {
    float mu = 0.f;
    for (int t = 0; t < 20; ++t) mu += z_all[t * 128 + tid];
    mu *= (1.f / 20.f);
    float var = 0.f;
    for (int t = 0; t < 20; ++t) {
      float dd = z_all[t * 128 + tid] - mu;
      var = fmaf(dd, dd, var);
    }
    var *= (1.f / 19.f);
    float inv = 1.f / sqrtf(var + EPSF);
    float ga = gamma[tid], be = beta[tid];
    for (int t = 0; t < 20; ++t)
      z_all[t * 128 + tid] = fmaf((z_all[t * 128 + tid] - mu) * inv, ga, be);
  }
  for (int idx = tid; idx < 20 * 256; idx += 256)
    Msh[(idx >> 8) * 257 + (idx & 255)] = mem_init[idx];
  hsh[tid] = 0.f;
  inp[128 + tid] = 0.f;
  float c_reg = 0.f;
  __syncthreads();
  const int u = tid;
  for (int t = 0; t < 20; ++t) {
    if (u < 128) inp[u] = z_all[t * 128 + u];
    __syncthreads();
    float a[4];
    for (int g = 0; g < 4; ++g) {
      int row = g * 256 + u;
      float acc = lb[row];
      const float* wr = wi + row * 384;
      for (int k = 0; k < 384; ++k) acc = fmaf(wr[k], inp[k], acc);
      const float* hr = wh + row * 256;
      for (int k = 0; k < 256; ++k) acc = fmaf(hr[k], hsh[k], acc);
      a[g] = acc;
    }
    __syncthreads();
    {
      float ig = 1.f / (1.f + expf(-a[0]));
      float fg = 1.f / (1.f + expf(-a[1]));
      float gg = tanhf(a[2]);
      float og = 1.f / (1.f + expf(-a[3]));
      c_reg = fg * c_reg + ig * gg;
      hsh[u] = og * tanhf(c_reg);
    }
    __syncthreads();
    {
      float sk = 0.f, sw = 0.f, sv = 0.f;
      const float* rk = wk + u * 256;
      const float* rw = wwk + u * 256;
      const float* rv = wv + u * 256;
      for (int k = 0; k < 256; ++k) {
        float hv = hsh[k];
        sk = fmaf(rk[k], hv, sk);
        sw = fmaf(rw[k], hv, sw);
        sv = fmaf(rv[k], hv, sv);
      }
      kqr[u] = sk;
      kqw[u] = sw;
      vsh[u] = tanhf(sv);
    }
    __syncthreads();
    if (u < 20) {
      const float* Mr = &Msh[u * 257];
      float ss = 0.f, s1 = 0.f, s2 = 0.f;
      for (int k = 0; k < 256; ++k) {
        float m = Mr[k];
        ss = fmaf(m, m, ss);
        s1 = fmaf(kqr[k], m, s1);
        s2 = fmaf(kqw[k], m, s2);
      }
      float inv = 1.f / (sqrtf(ss) + EPSF);
      simr[u] = s1 * inv;
      simw[u] = s2 * inv;
    } else if (u == 20 || u == 21) {
      const float* q = (u == 20) ? kqr : kqw;
      float qq = 0.f;
      for (int k = 0; k < 256; ++k) qq = fmaf(q[k], q[k], qq);
      invq[u - 20] = 1.f / (sqrtf(qq) + EPSF);
    }
    __syncthreads();
    if (u < 2) {
      const float* sims = (u == 0) ? simr : simw;
      float inv = invq[u];
      unsigned mask = 0;
      float tv[4];
      int ti[4];
      for (int j = 0; j < 4; ++j) {
        float best = -3.4e38f;
        int bx = 0;
        for (int n = 0; n < 20; ++n)
          if (!((mask >> n) & 1u) && sims[n] > best) { best = sims[n]; bx = n; }
        mask |= 1u << bx;
        tv[j] = best * inv;
        ti[j] = bx;
      }
      float e1 = expf(tv[1] - tv[0]);
      float e2 = expf(tv[2] - tv[0]);
      float e3 = expf(tv[3] - tv[0]);
      float s = 1.f + e1 + e2 + e3;
      wsel[u][0] = 1.f / s; wsel[u][1] = e1 / s; wsel[u][2] = e2 / s; wsel[u][3] = e3 / s;
      isel[u][0] = ti[0]; isel[u][1] = ti[1]; isel[u][2] = ti[2]; isel[u][3] = ti[3];
    }
    __syncthreads();
    {
      float rvv = 0.f;
      for (int j = 0; j < 4; ++j)
        rvv = fmaf(wsel[0][j], Msh[isel[0][j] * 257 + u], rvv);
      float vv = vsh[u];
      for (int j = 0; j < 4; ++j)
        Msh[isel[1][j] * 257 + u] += wsel[1][j] * vv;
      inp[128 + u] = rvv;
    }
    __syncthreads();
  }
  if (u < 4) {
    float acc = wob[u];
    const float* wr = wo + u * 512;
    for (int k = 0; k < 256; ++k) acc = fmaf(wr[k], hsh[k], acc);
    for (int k = 0; k < 256; ++k) acc = fmaf(wr[256 + k], inp[128 + k], acc);
    ysh[u] = acc;
    out[b * 4 + u] = acc;
  }
  __syncthreads();
  if (u == 0) {
    float best = ysh[0];
    int bx = 0;
    for (int o = 1; o < 4; ++o)
      if (ysh[o] > best) { best = ysh[o]; bx = o; }
    out[1024 + b] = (float)bx;
  }
}

// ---------- launch ----------
extern "C" void kernel_launch(void* const* d_in, const int* in_sizes, int n_in,
                              void* d_out, int out_size, void* d_ws, size_t ws_size,
                              hipStream_t stream) {
  const float* x    = (const float*)d_in[0];
  const float* c1w  = (const float*)d_in[1];
  const float* c1b  = (const float*)d_in[2];
  const float* c2w  = (const float*)d_in[3];
  const float* c2b  = (const float*)d_in[4];
  const float* c3w  = (const float*)d_in[5];
  const float* c3b  = (const float*)d_in[6];
  const float* f1w  = (const float*)d_in[7];
  const float* f1b  = (const float*)d_in[8];
  const float* f2w  = (const float*)d_in[9];
  const float* f2b  = (const float*)d_in[10];
  const float* gam  = (const float*)d_in[11];
  const float* bet  = (const float*)d_in[12];
  const float* wi   = (const float*)d_in[13];
  const float* wh   = (const float*)d_in[14];
  const float* lb   = (const float*)d_in[15];
  const float* wk   = (const float*)d_in[16];
  const float* wwk  = (const float*)d_in[17];
  const float* wv   = (const float*)d_in[18];
  const float* wo   = (const float*)d_in[19];
  const float* wob  = (const float*)d_in[20];
  const float* mem0 = (const float*)d_in[21];
  float* out = (float*)d_out;

  if (ws_size >= (size_t)WS_FLOATS * sizeof(float)) {
    float* ws = (float*)d_ws;
    pack_kernel<<<4224, 256, 0, stream>>>(wi, wh, wk, wwk, wv, f1w, f2w, ws);
    enc_kernel<<<5120, 256, 0, stream>>>(x, c1w, c1b, c2w, c2b, c3w, c3b,
                                         f1b, f2b, ws);
    norm_kernel<<<128, 256, 0, stream>>>(ws, gam, bet);
    scan_kernel<<<128, 256, 0, stream>>>(ws, lb, wo, wob, mem0, out);
  } else {
    fused_kernel<<<256, 256, 0, stream>>>(x, c1w, c1b, c2w, c2b, c3w, c3b,
                                          f1w, f1b, f2w, f2b, gam, bet,
                                          wi, wh, lb, wk, wwk, wv, wo, wob,
                                          mem0, out);
  }
}

// Round 6
// 1329.869 us; speedup vs baseline: 4.5364x; 1.3227x over previous
//
#include <hip/hip_runtime.h>
#include <hip/hip_bf16.h>

#define EPSF 1e-8f

// ---- workspace layout (floats) ----
#define OFF_WIT 0               // wiT [384][1024]
#define N_WIT   393216
#define OFF_WHT 393216          // whT [256][1024]
#define N_WHT   262144
#define OFF_PKT 655360          // pkT [256k][256o][4] = {wk,wwk,wv,0}
#define N_PKT   262144
#define OFF_F1T 917504          // f1T4 [128 k4][256 o] float4 = f1w[o][4k4..]
#define N_F1T   131072
#define OFF_F2T 1048576         // f2T4 [64 k4][128 o] float4
#define N_F2T   32768
#define OFF_Z   1081344         // z [5120][128]
#define N_Z     655360
#define WS_FLOATS 1736704       // 6,946,816 bytes

// ---------- pack: transpose weights into ws (once per launch) ----------
__global__ __launch_bounds__(256) void pack_kernel(
    const float* __restrict__ wi, const float* __restrict__ wh,
    const float* __restrict__ wk, const float* __restrict__ wwk,
    const float* __restrict__ wv,
    const float* __restrict__ f1w, const float* __restrict__ f2w,
    float* __restrict__ ws) {
  int id = blockIdx.x * 256 + threadIdx.x;
  if (id < N_WIT) {  // out[k*1024 + r] = wi[r*384 + k]
    int k = id >> 10, r = id & 1023;
    ws[OFF_WIT + id] = wi[r * 384 + k];
    return;
  }
  id -= N_WIT;
  if (id < N_WHT) {
    int k = id >> 10, r = id & 1023;
    ws[OFF_WHT + id] = wh[r * 256 + k];
    return;
  }
  id -= N_WHT;
  if (id < N_PKT) {  // out[((k*256)+o)*4 + m]
    int m = id & 3, o = (id >> 2) & 255, k = id >> 10;
    float v = 0.f;
    if (m == 0) v = wk[o * 256 + k];
    else if (m == 1) v = wwk[o * 256 + k];
    else if (m == 2) v = wv[o * 256 + k];
    ws[OFF_PKT + id] = v;
    return;
  }
  id -= N_PKT;
  if (id < N_F1T) {  // float4 per k-quad: ws[(k4*256+o)*4+m] = f1w[o*512+4k4+m]
    int m = id & 3, o = (id >> 2) & 255, k4 = id >> 10;
    ws[OFF_F1T + id] = f1w[o * 512 + k4 * 4 + m];
    return;
  }
  id -= N_F1T;
  if (id < N_F2T) {  // ws[(k4*128+o)*4+m] = f2w[o*256+4k4+m]
    int m = id & 3, o = (id >> 2) & 127, k4 = id >> 9;
    ws[OFF_F2T + id] = f2w[o * 256 + k4 * 4 + m];
  }
}

// ---------- encoder: one block per frame; register patches + uniform weights ----------
__global__ __launch_bounds__(256) void enc_kernel(
    const float* __restrict__ x,
    const float* __restrict__ w1, const float* __restrict__ b1,
    const float* __restrict__ w2, const float* __restrict__ b2,
    const float* __restrict__ w3, const float* __restrict__ b3,
    const float* __restrict__ f1b, const float* __restrict__ f2b,
    float* __restrict__ ws) {
  __shared__ __align__(16) float xs[1024];        // 32x32
  __shared__ __align__(16) float c1s[512 * 19];   // 32ch x 16 rows, pad 19
  __shared__ __align__(16) float c2s[256 * 9];    // 32ch x 8 rows, pad 9
  __shared__ __align__(16) float c3s[512];        // 32 x 4 x 4 (NCHW flatten)
  __shared__ __align__(16) float h1s[256];

  const float4* __restrict__ f1T4 = (const float4*)(ws + OFF_F1T);
  const float4* __restrict__ f2T4 = (const float4*)(ws + OFF_F2T);
  float* __restrict__ z = ws + OFF_Z;

  const int f = blockIdx.x;  // = b*20 + t
  const int tid = threadIdx.x;

  for (int i = tid; i < 1024; i += 256) xs[i] = x[f * 1024 + i];
  __syncthreads();

  // conv1: thread = pixel (16x16); patch in regs; 32 ocs with uniform weights
  {
    int oy = tid >> 4, ox = tid & 15;
    float patch[16];
    #pragma unroll
    for (int ky = 0; ky < 4; ++ky) {
      int iy = oy * 2 - 1 + ky;
      #pragma unroll
      for (int kx = 0; kx < 4; ++kx) {
        int ix = ox * 2 - 1 + kx;
        patch[ky * 4 + kx] =
            ((unsigned)iy <= 31u && (unsigned)ix <= 31u) ? xs[iy * 32 + ix] : 0.f;
      }
    }
    for (int oc = 0; oc < 32; ++oc) {
      float acc = b1[oc];
      #pragma unroll
      for (int k = 0; k < 16; ++k) acc = fmaf(patch[k], w1[oc * 16 + k], acc);
      c1s[(oc * 16 + oy) * 19 + ox] = fmaxf(acc, 0.f);
    }
  }
  __syncthreads();

  // conv2: wave og handles ocs og*8..+7; lane = pixel of 8x8; patch regs per ic
  {
    int pix = tid & 63;
    int og = __builtin_amdgcn_readfirstlane(tid >> 6);
    int oy = pix >> 3, ox = pix & 7;
    float acc[8];
    #pragma unroll
    for (int j = 0; j < 8; ++j) acc[j] = b2[og * 8 + j];
    for (int ic = 0; ic < 32; ++ic) {
      float patch[16];
      #pragma unroll
      for (int ky = 0; ky < 4; ++ky) {
        int iy = oy * 2 - 1 + ky;
        #pragma unroll
        for (int kx = 0; kx < 4; ++kx) {
          int ix = ox * 2 - 1 + kx;
          patch[ky * 4 + kx] = ((unsigned)iy <= 15u && (unsigned)ix <= 15u)
                                   ? c1s[(ic * 16 + iy) * 19 + ix] : 0.f;
        }
      }
      #pragma unroll
      for (int j = 0; j < 8; ++j) {
        const float* wr = w2 + ((og * 8 + j) * 32 + ic) * 16;  // wave-uniform
        #pragma unroll
        for (int k = 0; k < 16; ++k) acc[j] = fmaf(patch[k], wr[k], acc[j]);
      }
    }
    #pragma unroll
    for (int j = 0; j < 8; ++j)
      c2s[((og * 8 + j) * 8 + oy) * 9 + ox] = fmaxf(acc[j], 0.f);
  }
  __syncthreads();

  // conv3: thread = (pixel of 4x4, grp of 2 ocs); patch regs per ic
  {
    int pix = tid & 15, grp = tid >> 4;
    int oy = pix >> 2, ox = pix & 3;
    float a0 = b3[grp * 2], a1 = b3[grp * 2 + 1];
    for (int ic = 0; ic < 32; ++ic) {
      float patch[16];
      #pragma unroll
      for (int ky = 0; ky < 4; ++ky) {
        int iy = oy * 2 - 1 + ky;
        #pragma unroll
        for (int kx = 0; kx < 4; ++kx) {
          int ix = ox * 2 - 1 + kx;
          patch[ky * 4 + kx] = ((unsigned)iy <= 7u && (unsigned)ix <= 7u)
                                   ? c2s[(ic * 8 + iy) * 9 + ix] : 0.f;
        }
      }
      const float4* wa = (const float4*)(w3 + ((grp * 2 + 0) * 32 + ic) * 16);
      const float4* wb = (const float4*)(w3 + ((grp * 2 + 1) * 32 + ic) * 16);
      #pragma unroll
      for (int q = 0; q < 4; ++q) {
        float4 qa = wa[q], qb = wb[q];
        a0 = fmaf(patch[q * 4 + 0], qa.x, a0);
        a0 = fmaf(patch[q * 4 + 1], qa.y, a0);
        a0 = fmaf(patch[q * 4 + 2], qa.z, a0);
        a0 = fmaf(patch[q * 4 + 3], qa.w, a0);
        a1 = fmaf(patch[q * 4 + 0], qb.x, a1);
        a1 = fmaf(patch[q * 4 + 1], qb.y, a1);
        a1 = fmaf(patch[q * 4 + 2], qb.z, a1);
        a1 = fmaf(patch[q * 4 + 3], qb.w, a1);
      }
    }
    c3s[(grp * 2 + 0) * 16 + pix] = fmaxf(a0, 0.f);
    c3s[(grp * 2 + 1) * 16 + pix] = fmaxf(a1, 0.f);
  }
  __syncthreads();

  // fc1: 512 -> 256, relu; coalesced float4 weights
  {
    float acc = f1b[tid];
    for (int k4 = 0; k4 < 128; ++k4) {
      float4 cv = ((const float4*)c3s)[k4];
      float4 w = f1T4[k4 * 256 + tid];
      acc = fmaf(w.x, cv.x, acc);
      acc = fmaf(w.y, cv.y, acc);
      acc = fmaf(w.z, cv.z, acc);
      acc = fmaf(w.w, cv.w, acc);
    }
    h1s[tid] = fmaxf(acc, 0.f);
  }
  __syncthreads();

  // fc2: 256 -> 128, relu -> z
  if (tid < 128) {
    float acc = f2b[tid];
    for (int k4 = 0; k4 < 64; ++k4) {
      float4 hv = ((const float4*)h1s)[k4];
      float4 w = f2T4[k4 * 128 + tid];
      acc = fmaf(w.x, hv.x, acc);
      acc = fmaf(w.y, hv.y, acc);
      acc = fmaf(w.z, hv.z, acc);
      acc = fmaf(w.w, hv.w, acc);
    }
    z[f * 128 + tid] = fmaxf(acc, 0.f);
  }
}

// ---------- context norm over time ----------
__global__ __launch_bounds__(256) void norm_kernel(
    float* __restrict__ ws,
    const float* __restrict__ gamma, const float* __restrict__ beta) {
  float* z = ws + OFF_Z;
  int g = blockIdx.x * 256 + threadIdx.x;  // B*D = 32768
  int b = g >> 7, d = g & 127;
  float vals[20];
  float mu = 0.f;
  #pragma unroll
  for (int t = 0; t < 20; ++t) {
    float v = z[(b * 20 + t) * 128 + d];
    vals[t] = v;
    mu += v;
  }
  mu *= (1.f / 20.f);
  float var = 0.f;
  #pragma unroll
  for (int t = 0; t < 20; ++t) {
    float dd = vals[t] - mu;
    var = fmaf(dd, dd, var);
  }
  var *= (1.f / 19.f);
  float inv = 1.f / sqrtf(var + EPSF);
  float ga = gamma[d], be = beta[d];
  #pragma unroll
  for (int t = 0; t < 20; ++t)
    z[(b * 20 + t) * 128 + d] = fmaf((vals[t] - mu) * inv, ga, be);
}

// ---------- scan: 2 batch elements per block, 128 blocks (unchanged, proven) ----------
__global__ __launch_bounds__(256) void scan_kernel(
    const float* __restrict__ ws,
    const float* __restrict__ lb, const float* __restrict__ wo,
    const float* __restrict__ wob, const float* __restrict__ mem_init,
    float* __restrict__ out) {
  __shared__ float Msh[2][20 * 257];
  __shared__ __align__(16) float gsh[2][1024];
  __shared__ __align__(16) float inp[2][384];   // [z(128) | r(256)]
  __shared__ __align__(16) float hsh[2][256];
  __shared__ float kq[2][2][256];               // [bl][head][k]
  __shared__ float vsh[2][256];
  __shared__ float sims[2][2][20];
  __shared__ float invq[2][2];
  __shared__ float wsel[2][2][4];
  __shared__ int isel[2][2][4];
  __shared__ float ysh[2][4];

  const int u = threadIdx.x;
  const int b0 = blockIdx.x * 2;
  const float4* wiT4 = (const float4*)(ws + OFF_WIT);
  const float4* whT4 = (const float4*)(ws + OFF_WHT);
  const float4* pkT4 = (const float4*)(ws + OFF_PKT);
  const float* zz = ws + OFF_Z;

  #pragma unroll
  for (int bl = 0; bl < 2; ++bl)
    for (int idx = u; idx < 5120; idx += 256)
      Msh[bl][(idx >> 8) * 257 + (idx & 255)] = mem_init[idx];
  hsh[0][u] = 0.f; hsh[1][u] = 0.f;
  inp[0][128 + u] = 0.f; inp[1][128 + u] = 0.f;
  float c0 = 0.f, c1 = 0.f;
  const float4 bias = ((const float4*)lb)[u];  // rows 4u..4u+3
  __syncthreads();

  for (int t = 0; t < 20; ++t) {
    if (u < 128) {
      inp[0][u] = zz[(b0 * 20 + t) * 128 + u];
      inp[1][u] = zz[((b0 + 1) * 20 + t) * 128 + u];
    }
    __syncthreads();

    float A0[4] = {bias.x, bias.y, bias.z, bias.w};
    float A1[4] = {bias.x, bias.y, bias.z, bias.w};
    for (int k4 = 0; k4 < 96; ++k4) {
      float4 i0 = ((const float4*)inp[0])[k4];
      float4 i1 = ((const float4*)inp[1])[k4];
      float f0[4] = {i0.x, i0.y, i0.z, i0.w};
      float f1[4] = {i1.x, i1.y, i1.z, i1.w};
      #pragma unroll
      for (int j = 0; j < 4; ++j) {
        float4 w = wiT4[(k4 * 4 + j) * 256 + u];
        A0[0] = fmaf(w.x, f0[j], A0[0]); A0[1] = fmaf(w.y, f0[j], A0[1]);
        A0[2] = fmaf(w.z, f0[j], A0[2]); A0[3] = fmaf(w.w, f0[j], A0[3]);
        A1[0] = fmaf(w.x, f1[j], A1[0]); A1[1] = fmaf(w.y, f1[j], A1[1]);
        A1[2] = fmaf(w.z, f1[j], A1[2]); A1[3] = fmaf(w.w, f1[j], A1[3]);
      }
    }
    for (int k4 = 0; k4 < 64; ++k4) {
      float4 h0 = ((const float4*)hsh[0])[k4];
      float4 h1 = ((const float4*)hsh[1])[k4];
      float f0[4] = {h0.x, h0.y, h0.z, h0.w};
      float f1[4] = {h1.x, h1.y, h1.z, h1.w};
      #pragma unroll
      for (int j = 0; j < 4; ++j) {
        float4 w = whT4[(k4 * 4 + j) * 256 + u];
        A0[0] = fmaf(w.x, f0[j], A0[0]); A0[1] = fmaf(w.y, f0[j], A0[1]);
        A0[2] = fmaf(w.z, f0[j], A0[2]); A0[3] = fmaf(w.w, f0[j], A0[3]);
        A1[0] = fmaf(w.x, f1[j], A1[0]); A1[1] = fmaf(w.y, f1[j], A1[1]);
        A1[2] = fmaf(w.z, f1[j], A1[2]); A1[3] = fmaf(w.w, f1[j], A1[3]);
      }
    }
    ((float4*)gsh[0])[u] = make_float4(A0[0], A0[1], A0[2], A0[3]);
    ((float4*)gsh[1])[u] = make_float4(A1[0], A1[1], A1[2], A1[3]);
    __syncthreads();

    {
      float i0 = gsh[0][u], fg0 = gsh[0][256 + u], g0 = gsh[0][512 + u], o0 = gsh[0][768 + u];
      float i1 = gsh[1][u], fg1 = gsh[1][256 + u], g1 = gsh[1][512 + u], o1 = gsh[1][768 + u];
      c0 = (1.f / (1.f + expf(-fg0))) * c0 + (1.f / (1.f + expf(-i0))) * tanhf(g0);
      c1 = (1.f / (1.f + expf(-fg1))) * c1 + (1.f / (1.f + expf(-i1))) * tanhf(g1);
      hsh[0][u] = (1.f / (1.f + expf(-o0))) * tanhf(c0);
      hsh[1][u] = (1.f / (1.f + expf(-o1))) * tanhf(c1);
    }
    __syncthreads();

    {
      float sk0 = 0.f, sk1 = 0.f, sw0 = 0.f, sw1 = 0.f, sv0 = 0.f, sv1 = 0.f;
      for (int k4 = 0; k4 < 64; ++k4) {
        float4 h0 = ((const float4*)hsh[0])[k4];
        float4 h1 = ((const float4*)hsh[1])[k4];
        float f0[4] = {h0.x, h0.y, h0.z, h0.w};
        float f1[4] = {h1.x, h1.y, h1.z, h1.w};
        #pragma unroll
        for (int j = 0; j < 4; ++j) {
          float4 w = pkT4[(k4 * 4 + j) * 256 + u];
          sk0 = fmaf(w.x, f0[j], sk0); sk1 = fmaf(w.x, f1[j], sk1);
          sw0 = fmaf(w.y, f0[j], sw0); sw1 = fmaf(w.y, f1[j], sw1);
          sv0 = fmaf(w.z, f0[j], sv0); sv1 = fmaf(w.z, f1[j], sv1);
        }
      }
      kq[0][0][u] = sk0; kq[0][1][u] = sw0; vsh[0][u] = tanhf(sv0);
      kq[1][0][u] = sk1; kq[1][1][u] = sw1; vsh[1][u] = tanhf(sv1);
    }
    __syncthreads();

    if (u < 160) {
      int n = u >> 3, l = u & 7;
      #pragma unroll
      for (int bl = 0; bl < 2; ++bl) {
        const float* Mr = &Msh[bl][n * 257];
        float ss = 0.f, s1 = 0.f, s2 = 0.f;
        for (int i = 0; i < 32; ++i) {
          int k = l + 8 * i;
          float m = Mr[k];
          ss = fmaf(m, m, ss);
          s1 = fmaf(kq[bl][0][k], m, s1);
          s2 = fmaf(kq[bl][1][k], m, s2);
        }
        ss += __shfl_xor(ss, 1); s1 += __shfl_xor(s1, 1); s2 += __shfl_xor(s2, 1);
        ss += __shfl_xor(ss, 2); s1 += __shfl_xor(s1, 2); s2 += __shfl_xor(s2, 2);
        ss += __shfl_xor(ss, 4); s1 += __shfl_xor(s1, 4); s2 += __shfl_xor(s2, 4);
        if (l == 0) {
          float inv = 1.f / (sqrtf(ss) + EPSF);
          sims[bl][0][n] = s1 * inv;
          sims[bl][1][n] = s2 * inv;
        }
      }
    } else if (u < 164) {
      int bl2 = (u - 160) >> 1, hd = u & 1;
      float qq = 0.f;
      for (int k = 0; k < 256; ++k) {
        float q = kq[bl2][hd][k];
        qq = fmaf(q, q, qq);
      }
      invq[bl2][hd] = 1.f / (sqrtf(qq) + EPSF);
    }
    __syncthreads();

    if (u < 4) {
      int bl = u >> 1, hd = u & 1;
      const float* sm = sims[bl][hd];
      float inv = invq[bl][hd];
      unsigned mask = 0;
      float tv[4];
      int ti[4];
      for (int j = 0; j < 4; ++j) {
        float best = -3.4e38f;
        int bx = 0;
        for (int n = 0; n < 20; ++n)
          if (!((mask >> n) & 1u) && sm[n] > best) { best = sm[n]; bx = n; }
        mask |= 1u << bx;
        tv[j] = best * inv;
        ti[j] = bx;
      }
      float e0 = 1.f;
      float e1 = expf(tv[1] - tv[0]);
      float e2 = expf(tv[2] - tv[0]);
      float e3 = expf(tv[3] - tv[0]);
      float s = e0 + e1 + e2 + e3;
      wsel[bl][hd][0] = e0 / s; wsel[bl][hd][1] = e1 / s;
      wsel[bl][hd][2] = e2 / s; wsel[bl][hd][3] = e3 / s;
      isel[bl][hd][0] = ti[0]; isel[bl][hd][1] = ti[1];
      isel[bl][hd][2] = ti[2]; isel[bl][hd][3] = ti[3];
    }
    __syncthreads();

    #pragma unroll
    for (int bl = 0; bl < 2; ++bl) {
      float rvv = 0.f;
      #pragma unroll
      for (int j = 0; j < 4; ++j)
        rvv = fmaf(wsel[bl][0][j], Msh[bl][isel[bl][0][j] * 257 + u], rvv);
      float vv = vsh[bl][u];
      #pragma unroll
      for (int j = 0; j < 4; ++j)
        Msh[bl][isel[bl][1][j] * 257 + u] += wsel[bl][1][j] * vv;
      inp[bl][128 + u] = rvv;
    }
    __syncthreads();
  }

  if (u < 8) {
    int bl = u >> 2, o = u & 3;
    float acc = wob[o];
    const float* wr = wo + o * 512;
    for (int k = 0; k < 256; ++k) acc = fmaf(wr[k], hsh[bl][k], acc);
    for (int k = 0; k < 256; ++k) acc = fmaf(wr[256 + k], inp[bl][128 + k], acc);
    ysh[bl][o] = acc;
    out[(b0 + bl) * 4 + o] = acc;
  }
  __syncthreads();
  if (u < 2) {
    float best = ysh[u][0];
    int bx = 0;
    #pragma unroll
    for (int o = 1; o < 4; ++o)
      if (ysh[u][o] > best) { best = ysh[u][o]; bx = o; }
    out[1024 + b0 + u] = (float)bx;
  }
}

// ---------- fallback: proven round-4 single fused kernel (no workspace) ----------
__global__ __launch_bounds__(256) void fused_kernel(
    const float* __restrict__ x,
    const float* __restrict__ w1, const float* __restrict__ b1,
    const float* __restrict__ w2, const float* __restrict__ b2,
    const float* __restrict__ w3, const float* __restrict__ b3,
    const float* __restrict__ f1w, const float* __restrict__ f1b,
    const float* __restrict__ f2w, const float* __restrict__ f2b,
    const float* __restrict__ gamma, const float* __restrict__ beta,
    const float* __restrict__ wi, const float* __restrict__ wh,
    const float* __restrict__ lb, const float* __restrict__ wk,
    const float* __restrict__ wwk, const float* __restrict__ wv,
    const float* __restrict__ wo, const float* __restrict__ wob,
    const float* __restrict__ mem_init, float* __restrict__ out) {
  __shared__ float smem[15104];
  __shared__ float simr[20], simw[20], invq[2], wsel[2][4], ysh[4];
  __shared__ int isel[2][4];
  float* z_all = smem;
  float* pool = smem + 2560;
  float* xs = pool;
  float* c1s = pool + 1024;
  float* c2s = pool + 9216;
  float* c3s = pool + 11264;
  float* h1s = pool + 11776;
  float* w1s = pool + 12032;
  float* Msh = pool;
  float* inp = pool + 5140;
  float* hsh = pool + 5524;
  float* kqr = pool + 5780;
  float* kqw = pool + 6036;
  float* vsh = pool + 6292;
  const int tid = threadIdx.x;
  const int b = blockIdx.x;
  for (int i = tid; i < 512; i += 256) w1s[i] = w1[i];
  for (int f = 0; f < 20; ++f) {
    for (int i = tid; i < 1024; i += 256) xs[i] = x[(b * 20 + f) * 1024 + i];
    __syncthreads();
    for (int i = 0; i < 32; ++i) {
      int idx = i * 256 + tid;
      int oc = idx >> 8, pix = idx & 255, oy = pix >> 4, ox = pix & 15;
      float acc = b1[oc];
      for (int ky = 0; ky < 4; ++ky) {
        int iy = oy * 2 - 1 + ky;
        if ((unsigned)iy > 31u) continue;
        for (int kx = 0; kx < 4; ++kx) {
          int ix = ox * 2 - 1 + kx;
          if ((unsigned)ix > 31u) continue;
          acc = fmaf(xs[iy * 32 + ix], w1s[oc * 16 + ky * 4 + kx], acc);
        }
      }
      c1s[idx] = fmaxf(acc, 0.f);
    }
    __syncthreads();
    {
      int oc = tid >> 3, pg = tid & 7;
      float acc[8];
      float bb = b2[oc];
      for (int i = 0; i < 8; ++i) acc[i] = bb;
      for (int ic = 0; ic < 32; ++ic) {
        const float* in = &c1s[ic * 256];
        const float* wv_ = &w2[(oc * 32 + ic) * 16];
        for (int i = 0; i < 8; ++i) {
          int p = pg + 8 * i;
          int oy = p >> 3, ox = p & 7;
          for (int ky = 0; ky < 4; ++ky) {
            int iy = oy * 2 - 1 + ky;
            if ((unsigned)iy > 15u) continue;
            for (int kx = 0; kx < 4; ++kx) {
              int ix = ox * 2 - 1 + kx;
              if ((unsigned)ix > 15u) continue;
              acc[i] = fmaf(in[iy * 16 + ix], wv_[ky * 4 + kx], acc[i]);
            }
          }
        }
      }
      for (int i = 0; i < 8; ++i) c2s[oc * 64 + pg + 8 * i] = fmaxf(acc[i], 0.f);
    }
    __syncthreads();
    {
      int oc = tid >> 3, pg = tid & 7;
      float bb = b3[oc];
      float acc0 = bb, acc1 = bb;
      int p0 = pg, p1 = pg + 8;
      int oy0 = p0 >> 2, ox0 = p0 & 3, oy1 = p1 >> 2, ox1 = p1 & 3;
      for (int ic = 0; ic < 32; ++ic) {
        const float* in = &c2s[ic * 64];
        const float* wv_ = &w3[(oc * 32 + ic) * 16];
        for (int ky = 0; ky < 4; ++ky) {
          int iy0 = oy0 * 2 - 1 + ky, iy1 = oy1 * 2 - 1 + ky;
          for (int kx = 0; kx < 4; ++kx) {
            float w = wv_[ky * 4 + kx];
            int ix0 = ox0 * 2 - 1 + kx, ix1 = ox1 * 2 - 1 + kx;
            if ((unsigned)iy0 <= 7u && (unsigned)ix0 <= 7u)
              acc0 = fmaf(in[iy0 * 8 + ix0], w, acc0);
            if ((unsigned)iy1 <= 7u && (unsigned)ix1 <= 7u)
              acc1 = fmaf(in[iy1 * 8 + ix1], w, acc1);
          }
        }
      }
      c3s[oc * 16 + p0] = fmaxf(acc0, 0.f);
      c3s[oc * 16 + p1] = fmaxf(acc1, 0.f);
    }
    __syncthreads();
    {
      float acc = f1b[tid];
      const float* wr = f1w + tid * 512;
      for (int k = 0; k < 512; ++k) acc = fmaf(wr[k], c3s[k], acc);
      h1s[tid] = fmaxf(acc, 0.f);
    }
    __syncthreads();
    if (tid < 128) {
      float acc = f2b[tid];
      const float* wr = f2w + tid * 256;
      for (int k = 0; k < 256; ++k) acc = fmaf(wr[k], h1s[k], acc);
      z_all[f * 128 + tid] = fmaxf(acc, 0.f);
    }
    __syncthreads();
  }
  if (tid < 128) {
    float mu = 0.f;
    for (int t = 0; t < 20; ++t) mu += z_all[t * 128 + tid];
    mu *= (1.f / 20.f);
    float var = 0.f;
    for (int t = 0; t < 20; ++t) {
      float dd = z_all[t * 128 + tid] - mu;
      var = fmaf(dd, dd, var);
    }
    var *= (1.f / 19.f);
    float inv = 1.f / sqrtf(var + EPSF);
    float ga = gamma[tid], be = beta[tid];
    for (int t = 0; t < 20; ++t)
      z_all[t * 128 + tid] = fmaf((z_all[t * 128 + tid] - mu) * inv, ga, be);
  }
  for (int idx = tid; idx < 20 * 256; idx += 256)
    Msh[(idx >> 8) * 257 + (idx & 255)] = mem_init[idx];
  hsh[tid] = 0.f;
  inp[128 + tid] = 0.f;
  float c_reg = 0.f;
  __syncthreads();
  const int u = tid;
  for (int t = 0; t < 20; ++t) {
    if (u < 128) inp[u] = z_all[t * 128 + u];
    __syncthreads();
    float a[4];
    for (int g = 0; g < 4; ++g) {
      int row = g * 256 + u;
      float acc = lb[row];
      const float* wr = wi + row * 384;
      for (int k = 0; k < 384; ++k) acc = fmaf(wr[k], inp[k], acc);
      const float* hr = wh + row * 256;
      for (int k = 0; k < 256; ++k) acc = fmaf(hr[k], hsh[k], acc);
      a[g] = acc;
    }
    __syncthreads();
    {
      float ig = 1.f / (1.f + expf(-a[0]));
      float fg = 1.f / (1.f + expf(-a[1]));
      float gg = tanhf(a[2]);
      float og = 1.f / (1.f + expf(-a[3]));
      c_reg = fg * c_reg + ig * gg;
      hsh[u] = og * tanhf(c_reg);
    }
    __syncthreads();
    {
      float sk = 0.f, sw = 0.f, sv = 0.f;
      const float* rk = wk + u * 256;
      const float* rw = wwk + u * 256;
      const float* rv = wv + u * 256;
      for (int k = 0; k < 256; ++k) {
        float hv = hsh[k];
        sk = fmaf(rk[k], hv, sk);
        sw = fmaf(rw[k], hv, sw);
        sv = fmaf(rv[k], hv, sv);
      }
      kqr[u] = sk;
      kqw[u] = sw;
      vsh[u] = tanhf(sv);
    }
    __syncthreads();
    if (u < 20) {
      const float* Mr = &Msh[u * 257];
      float ss = 0.f, s1 = 0.f, s2 = 0.f;
      for (int k = 0; k < 256; ++k) {
        float m = Mr[k];
        ss = fmaf(m, m, ss);
        s1 = fmaf(kqr[k], m, s1);
        s2 = fmaf(kqw[k], m, s2);
      }
      float inv = 1.f / (sqrtf(ss) + EPSF);
      simr[u] = s1 * inv;
      simw[u] = s2 * inv;
    } else if (u == 20 || u == 21) {
      const float* q = (u == 20) ? kqr : kqw;
      float qq = 0.f;
      for (int k = 0; k < 256; ++k) qq = fmaf(q[k], q[k], qq);
      invq[u - 20] = 1.f / (sqrtf(qq) + EPSF);
    }
    __syncthreads();
    if (u < 2) {
      const float* sims = (u == 0) ? simr : simw;
      float inv = invq[u];
      unsigned mask = 0;
      float tv[4];
      int ti[4];
      for (int j = 0; j < 4; ++j) {
        float best = -3.4e38f;
        int bx = 0;
        for (int n = 0; n < 20; ++n)
          if (!((mask >> n) & 1u) && sims[n] > best) { best = sims[n]; bx = n; }
        mask |= 1u << bx;
        tv[j] = best * inv;
        ti[j] = bx;
      }
      float e1 = expf(tv[1] - tv[0]);
      float e2 = expf(tv[2] - tv[0]);
      float e3 = expf(tv[3] - tv[0]);
      float s = 1.f + e1 + e2 + e3;
      wsel[u][0] = 1.f / s; wsel[u][1] = e1 / s; wsel[u][2] = e2 / s; wsel[u][3] = e3 / s;
      isel[u][0] = ti[0]; isel[u][1] = ti[1]; isel[u][2] = ti[2]; isel[u][3] = ti[3];
    }
    __syncthreads();
    {
      float rvv = 0.f;
      for (int j = 0; j < 4; ++j)
        rvv = fmaf(wsel[0][j], Msh[isel[0][j] * 257 + u], rvv);
      float vv = vsh[u];
      for (int j = 0; j < 4; ++j)
        Msh[isel[1][j] * 257 + u] += wsel[1][j] * vv;
      inp[128 + u] = rvv;
    }
    __syncthreads();
  }
  if (u < 4) {
    float acc = wob[u];
    const float* wr = wo + u * 512;
    for (int k = 0; k < 256; ++k) acc = fmaf(wr[k], hsh[k], acc);
    for (int k = 0; k < 256; ++k) acc = fmaf(wr[256 + k], inp[128 + k], acc);
    ysh[u] = acc;
    out[b * 4 + u] = acc;
  }
  __syncthreads();
  if (u == 0) {
    float best = ysh[0];
    int bx = 0;
    for (int o = 1; o < 4; ++o)
      if (ysh[o] > best) { best = ysh[o]; bx = o; }
    out[1024 + b] = (float)bx;
  }
}

// ---------- launch ----------
extern "C" void kernel_launch(void* const* d_in, const int* in_sizes, int n_in,
                              void* d_out, int out_size, void* d_ws, size_t ws_size,
                              hipStream_t stream) {
  const float* x    = (const float*)d_in[0];
  const float* c1w  = (const float*)d_in[1];
  const float* c1b  = (const float*)d_in[2];
  const float* c2w  = (const float*)d_in[3];
  const float* c2b  = (const float*)d_in[4];
  const float* c3w  = (const float*)d_in[5];
  const float* c3b  = (const float*)d_in[6];
  const float* f1w  = (const float*)d_in[7];
  const float* f1b  = (const float*)d_in[8];
  const float* f2w  = (const float*)d_in[9];
  const float* f2b  = (const float*)d_in[10];
  const float* gam  = (const float*)d_in[11];
  const float* bet  = (const float*)d_in[12];
  const float* wi   = (const float*)d_in[13];
  const float* wh   = (const float*)d_in[14];
  const float* lb   = (const float*)d_in[15];
  const float* wk   = (const float*)d_in[16];
  const float* wwk  = (const float*)d_in[17];
  const float* wv   = (const float*)d_in[18];
  const float* wo   = (const float*)d_in[19];
  const float* wob  = (const float*)d_in[20];
  const float* mem0 = (const float*)d_in[21];
  float* out = (float*)d_out;

  if (ws_size >= (size_t)WS_FLOATS * sizeof(float)) {
    float* ws = (float*)d_ws;
    pack_kernel<<<4224, 256, 0, stream>>>(wi, wh, wk, wwk, wv, f1w, f2w, ws);
    enc_kernel<<<5120, 256, 0, stream>>>(x, c1w, c1b, c2w, c2b, c3w, c3b,
                                         f1b, f2b, ws);
    norm_kernel<<<128, 256, 0, stream>>>(ws, gam, bet);
    scan_kernel<<<128, 256, 0, stream>>>(ws, lb, wo, wob, mem0, out);
  } else {
    fused_kernel<<<256, 256, 0, stream>>>(x, c1w, c1b, c2w, c2b, c3w, c3b,
                                          f1w, f1b, f2w, f2b, gam, bet,
                                          wi, wh, lb, wk, wwk, wv, wo, wob,
                                          mem0, out);
  }
}